// Round 2
// baseline (1056.678 us; speedup 1.0000x reference)
//
#include <hip/hip_runtime.h>
#include <hip/hip_bf16.h>

#define B_ 2
#define T_ 2048
#define D_ 1024
#define H_ 16
#define DH_ 64

// ---------------------------------------------------------------------------
// Kernel 1: q = x @ Wq^T  (C[M=B*T][N=D], A=x[M][K], B=Wq[N][K], both K-major)
// Output written fp32 into workspace laid out as [B, H, T, DH].
// 64x64 tile, BK=32, 256 threads, each thread a 4x4 register tile.
// ---------------------------------------------------------------------------
__global__ __launch_bounds__(256) void qproj_kernel(
    const float* __restrict__ x,
    const float* __restrict__ Wq,
    float* __restrict__ q)
{
    const int BK = 32;
    __shared__ float As[64][33];   // +1 pad
    __shared__ float Bs[64][33];

    const int tid = threadIdx.x;
    const int tx = tid & 15;       // N direction (4 cols each)
    const int ty = tid >> 4;       // M direction (4 rows each)
    const int m0 = blockIdx.y * 64;
    const int n0 = blockIdx.x * 64;

    float c[4][4] = {};

    // loader: each thread moves 8 contiguous floats (two float4) per operand
    const int lrow = tid >> 2;           // 0..63
    const int lcol = (tid & 3) * 8;      // 0,8,16,24

    for (int k0 = 0; k0 < D_; k0 += BK) {
        {
            const float4 r0 = *(const float4*)(x + (size_t)(m0 + lrow) * D_ + k0 + lcol);
            const float4 r1 = *(const float4*)(x + (size_t)(m0 + lrow) * D_ + k0 + lcol + 4);
            As[lrow][lcol + 0] = r0.x; As[lrow][lcol + 1] = r0.y;
            As[lrow][lcol + 2] = r0.z; As[lrow][lcol + 3] = r0.w;
            As[lrow][lcol + 4] = r1.x; As[lrow][lcol + 5] = r1.y;
            As[lrow][lcol + 6] = r1.z; As[lrow][lcol + 7] = r1.w;
        }
        {
            const float4 r0 = *(const float4*)(Wq + (size_t)(n0 + lrow) * D_ + k0 + lcol);
            const float4 r1 = *(const float4*)(Wq + (size_t)(n0 + lrow) * D_ + k0 + lcol + 4);
            Bs[lrow][lcol + 0] = r0.x; Bs[lrow][lcol + 1] = r0.y;
            Bs[lrow][lcol + 2] = r0.z; Bs[lrow][lcol + 3] = r0.w;
            Bs[lrow][lcol + 4] = r1.x; Bs[lrow][lcol + 5] = r1.y;
            Bs[lrow][lcol + 6] = r1.z; Bs[lrow][lcol + 7] = r1.w;
        }
        __syncthreads();

        #pragma unroll
        for (int kk = 0; kk < BK; ++kk) {
            float a[4], b[4];
            #pragma unroll
            for (int i = 0; i < 4; ++i) a[i] = As[ty * 4 + i][kk];
            #pragma unroll
            for (int j = 0; j < 4; ++j) b[j] = Bs[tx * 4 + j][kk];
            #pragma unroll
            for (int i = 0; i < 4; ++i)
                #pragma unroll
                for (int j = 0; j < 4; ++j)
                    c[i][j] = fmaf(a[i], b[j], c[i][j]);
        }
        __syncthreads();
    }

    #pragma unroll
    for (int i = 0; i < 4; ++i) {
        const int m = m0 + ty * 4 + i;
        const int b = m / T_;
        const int t = m % T_;
        #pragma unroll
        for (int j = 0; j < 4; ++j) {
            const int n  = n0 + tx * 4 + j;
            const int h  = n >> 6;
            const int dh = n & 63;
            q[(((size_t)b * H_ + h) * T_ + t) * DH_ + dh] = c[i][j];
        }
    }
}

// ---------------------------------------------------------------------------
// Kernel 2: flash-style causal attention + residual.
// Block = 256 threads handles one (b, h, 64-row q-tile).
// K-tile LDS buffer is reused to hold P (exp(scores)) to stay < 64 KB static.
// ---------------------------------------------------------------------------
__global__ __launch_bounds__(256) void attn_kernel(
    const float* __restrict__ qw,     // [B,H,T,DH] fp32 (from qproj)
    const float* __restrict__ kg,     // [B,H,T,DH]
    const float* __restrict__ vg,     // [B,H,T,DH]
    const float* __restrict__ xg,     // [B,T,D]
    float* __restrict__ out)          // [B,T,D]
{
    __shared__ float Qs[64][65];
    __shared__ float KPs[64][65];  // K tile, then reused for P
    __shared__ float Vs[64][65];

    const int tid = threadIdx.x;
    const int tx = tid & 15;       // key/col direction (4 each)
    const int ty = tid >> 4;       // query/row direction (4 each)
    const int qt = blockIdx.x;
    const int h  = blockIdx.y;
    const int b  = blockIdx.z;
    const int q0 = qt * 64;
    const size_t bh = (size_t)b * H_ + h;
    const float scale = 1.0f / 32.0f;   // 1/sqrt(D)

    // load Q tile (pre-scaled): 4096 floats, 256 threads x 16
    {
        const int base = tid * 16;
        const int r = base >> 6, cl = base & 63;
        #pragma unroll
        for (int u = 0; u < 4; ++u) {
            const float4 v4 = *(const float4*)(qw + (bh * T_ + q0 + r) * DH_ + cl + u * 4);
            Qs[r][cl + u * 4 + 0] = v4.x * scale;
            Qs[r][cl + u * 4 + 1] = v4.y * scale;
            Qs[r][cl + u * 4 + 2] = v4.z * scale;
            Qs[r][cl + u * 4 + 3] = v4.w * scale;
        }
    }

    float m_i[4], l_i[4], acc[4][4] = {};
    #pragma unroll
    for (int i = 0; i < 4; ++i) { m_i[i] = -INFINITY; l_i[i] = 0.0f; }

    __syncthreads();

    const int kend = q0 + 64;
    for (int j0 = 0; j0 < kend; j0 += 64) {
        // load K and V tiles: 4096 floats each
        {
            const int base = tid * 16;
            const int r = base >> 6, cl = base & 63;
            #pragma unroll
            for (int u = 0; u < 4; ++u) {
                const float4 rk = *(const float4*)(kg + (bh * T_ + j0 + r) * DH_ + cl + u * 4);
                const float4 rv = *(const float4*)(vg + (bh * T_ + j0 + r) * DH_ + cl + u * 4);
                KPs[r][cl + u * 4 + 0] = rk.x; KPs[r][cl + u * 4 + 1] = rk.y;
                KPs[r][cl + u * 4 + 2] = rk.z; KPs[r][cl + u * 4 + 3] = rk.w;
                Vs[r][cl + u * 4 + 0]  = rv.x; Vs[r][cl + u * 4 + 1]  = rv.y;
                Vs[r][cl + u * 4 + 2]  = rv.z; Vs[r][cl + u * 4 + 3]  = rv.w;
            }
        }
        __syncthreads();

        // S = Q K^T (Q pre-scaled)
        float s[4][4] = {};
        #pragma unroll 8
        for (int kk = 0; kk < 64; ++kk) {
            float a[4], bb[4];
            #pragma unroll
            for (int i = 0; i < 4; ++i) a[i] = Qs[ty * 4 + i][kk];
            #pragma unroll
            for (int j = 0; j < 4; ++j) bb[j] = KPs[tx * 4 + j][kk];
            #pragma unroll
            for (int i = 0; i < 4; ++i)
                #pragma unroll
                for (int j = 0; j < 4; ++j)
                    s[i][j] = fmaf(a[i], bb[j], s[i][j]);
        }

        // causal mask (only the diagonal tile can have masked entries)
        if (j0 == q0) {
            #pragma unroll
            for (int i = 0; i < 4; ++i)
                #pragma unroll
                for (int j = 0; j < 4; ++j)
                    if (j0 + tx * 4 + j > q0 + ty * 4 + i) s[i][j] = -INFINITY;
        }

        __syncthreads();  // everyone done reading K before overwriting with P

        // online softmax update; write P into KPs
        #pragma unroll
        for (int i = 0; i < 4; ++i) {
            float rm = fmaxf(fmaxf(s[i][0], s[i][1]), fmaxf(s[i][2], s[i][3]));
            #pragma unroll
            for (int off = 1; off < 16; off <<= 1)
                rm = fmaxf(rm, __shfl_xor(rm, off, 16));
            const float mn = fmaxf(m_i[i], rm);
            const float alpha = __expf(m_i[i] - mn);   // m_i=-inf -> 0
            float rs = 0.0f;
            #pragma unroll
            for (int j = 0; j < 4; ++j) {
                s[i][j] = __expf(s[i][j] - mn);        // masked -> exp(-inf)=0
                rs += s[i][j];
            }
            #pragma unroll
            for (int off = 1; off < 16; off <<= 1)
                rs += __shfl_xor(rs, off, 16);
            l_i[i] = l_i[i] * alpha + rs;
            m_i[i] = mn;
            #pragma unroll
            for (int j = 0; j < 4; ++j) {
                acc[i][j] *= alpha;
                KPs[ty * 4 + i][tx * 4 + j] = s[i][j];
            }
        }
        __syncthreads();

        // acc += P @ V
        #pragma unroll 8
        for (int c0 = 0; c0 < 64; ++c0) {
            float a[4], bb[4];
            #pragma unroll
            for (int i = 0; i < 4; ++i) a[i] = KPs[ty * 4 + i][c0];
            #pragma unroll
            for (int j = 0; j < 4; ++j) bb[j] = Vs[c0][tx * 4 + j];
            #pragma unroll
            for (int i = 0; i < 4; ++i)
                #pragma unroll
                for (int j = 0; j < 4; ++j)
                    acc[i][j] = fmaf(a[i], bb[j], acc[i][j]);
        }
        __syncthreads();  // before next tile's K/V load overwrites
    }

    // epilogue: out = x + acc / l
    #pragma unroll
    for (int i = 0; i < 4; ++i) {
        const int t = q0 + ty * 4 + i;
        const float inv_l = 1.0f / l_i[i];
        #pragma unroll
        for (int j = 0; j < 4; ++j) {
            const int dcol = h * DH_ + tx * 4 + j;
            const size_t off = ((size_t)b * T_ + t) * D_ + dcol;
            out[off] = xg[off] + acc[i][j] * inv_l;
        }
    }
}

extern "C" void kernel_launch(void* const* d_in, const int* in_sizes, int n_in,
                              void* d_out, int out_size, void* d_ws, size_t ws_size,
                              hipStream_t stream) {
    const float* x  = (const float*)d_in[0];
    const float* k  = (const float*)d_in[1];
    const float* v  = (const float*)d_in[2];
    const float* Wq = (const float*)d_in[3];
    float* out = (float*)d_out;
    float* qws = (float*)d_ws;   // [B,H,T,DH] fp32 = 16.8 MB

    dim3 g1(D_ / 64, (B_ * T_) / 64);   // (16, 64)
    qproj_kernel<<<g1, 256, 0, stream>>>(x, Wq, qws);

    dim3 g2(T_ / 64, H_, B_);           // (32, 16, 2)
    attn_kernel<<<g2, 256, 0, stream>>>(qws, k, v, x, out);
}

// Round 3
// 274.461 us; speedup vs baseline: 3.8500x; 3.8500x over previous
//
#include <hip/hip_runtime.h>
#include <hip/hip_bf16.h>

#define B_ 2
#define T_ 2048
#define D_ 1024
#define H_ 16
#define DH_ 64

typedef __attribute__((ext_vector_type(8))) short bf16x8;
typedef __attribute__((ext_vector_type(4))) float f32x4;
typedef __attribute__((ext_vector_type(8))) unsigned short u16x8;

__device__ __forceinline__ unsigned short f2bf(float f) {
    unsigned int u = __float_as_uint(f);
    return (unsigned short)((u + 0x7FFFu + ((u >> 16) & 1u)) >> 16);
}

// ---------------------------------------------------------------------------
// Prepass 1: k fp32 -> kb bf16 (4M elements, 8/thread)
// ---------------------------------------------------------------------------
__global__ __launch_bounds__(256) void convk_kernel(const float* __restrict__ k,
                                                    unsigned short* __restrict__ kb) {
    const int i = (blockIdx.x * 256 + threadIdx.x) * 8;
    const float4 a = *(const float4*)(k + i);
    const float4 b = *(const float4*)(k + i + 4);
    u16x8 o;
    o[0] = f2bf(a.x); o[1] = f2bf(a.y); o[2] = f2bf(a.z); o[3] = f2bf(a.w);
    o[4] = f2bf(b.x); o[5] = f2bf(b.y); o[6] = f2bf(b.z); o[7] = f2bf(b.w);
    *(u16x8*)(kb + i) = o;
}

// ---------------------------------------------------------------------------
// Prepass 2: v[b,h,t,dh] fp32 -> vt[b,h,dh,t] bf16 (64x64 LDS tile transpose)
// ---------------------------------------------------------------------------
__global__ __launch_bounds__(256) void transv_kernel(const float* __restrict__ v,
                                                     unsigned short* __restrict__ vt) {
    __shared__ float Ts[64][65];
    const int tid = threadIdx.x;
    const int t0 = blockIdx.x * 64;
    const size_t bh = (size_t)blockIdx.z * H_ + blockIdx.y;
    #pragma unroll
    for (int u = 0; u < 4; ++u) {
        const int tr = u * 16 + (tid >> 4);
        const int dc = (tid & 15) * 4;
        const float4 r = *(const float4*)(v + (bh * T_ + t0 + tr) * DH_ + dc);
        Ts[tr][dc + 0] = r.x; Ts[tr][dc + 1] = r.y;
        Ts[tr][dc + 2] = r.z; Ts[tr][dc + 3] = r.w;
    }
    __syncthreads();
    #pragma unroll
    for (int u = 0; u < 4; ++u) {
        const int dh = u * 16 + (tid >> 4);
        const int tc = (tid & 15) * 4;
        ushort4 o;
        o.x = f2bf(Ts[tc + 0][dh]); o.y = f2bf(Ts[tc + 1][dh]);
        o.z = f2bf(Ts[tc + 2][dh]); o.w = f2bf(Ts[tc + 3][dh]);
        *(ushort4*)(vt + (bh * DH_ + dh) * T_ + t0 + tc) = o;
    }
}

// ---------------------------------------------------------------------------
// Kernel 1: qb = bf16( (x @ Wq^T) / 32 ), layout [B,H,T,DH]
// 128x128 tile, BK=32, 256 thr (4 waves 2x2, each 64x64), MFMA 16x16x32 bf16.
// fp32 global loads converted to bf16 during LDS staging.
// ---------------------------------------------------------------------------
__global__ __launch_bounds__(256) void qproj_kernel(const float* __restrict__ x,
                                                    const float* __restrict__ Wq,
                                                    unsigned short* __restrict__ qb) {
    __shared__ unsigned short As[128][40];   // +8 pad: stride 20 dw -> 2-way max
    __shared__ unsigned short Bs[128][40];

    const int tid = threadIdx.x;
    const int lane = tid & 63;
    const int w = tid >> 6;
    const int wm = w >> 1, wn = w & 1;
    const int l15 = lane & 15, l4 = lane >> 4;
    const int m0 = blockIdx.y * 128, n0 = blockIdx.x * 128;

    f32x4 acc[4][4] = {};

    const int srow = tid >> 1;           // 0..127
    const int scol = (tid & 1) * 16;     // 0 or 16

    for (int k0 = 0; k0 < D_; k0 += 32) {
        {
            const float* g = x + (size_t)(m0 + srow) * D_ + k0 + scol;
            const float4 f0 = *(const float4*)(g);
            const float4 f1 = *(const float4*)(g + 4);
            const float4 f2 = *(const float4*)(g + 8);
            const float4 f3 = *(const float4*)(g + 12);
            u16x8 p0, p1;
            p0[0] = f2bf(f0.x); p0[1] = f2bf(f0.y); p0[2] = f2bf(f0.z); p0[3] = f2bf(f0.w);
            p0[4] = f2bf(f1.x); p0[5] = f2bf(f1.y); p0[6] = f2bf(f1.z); p0[7] = f2bf(f1.w);
            p1[0] = f2bf(f2.x); p1[1] = f2bf(f2.y); p1[2] = f2bf(f2.z); p1[3] = f2bf(f2.w);
            p1[4] = f2bf(f3.x); p1[5] = f2bf(f3.y); p1[6] = f2bf(f3.z); p1[7] = f2bf(f3.w);
            *(u16x8*)&As[srow][scol] = p0;
            *(u16x8*)&As[srow][scol + 8] = p1;
        }
        {
            const float* g = Wq + (size_t)(n0 + srow) * D_ + k0 + scol;
            const float4 f0 = *(const float4*)(g);
            const float4 f1 = *(const float4*)(g + 4);
            const float4 f2 = *(const float4*)(g + 8);
            const float4 f3 = *(const float4*)(g + 12);
            u16x8 p0, p1;
            p0[0] = f2bf(f0.x); p0[1] = f2bf(f0.y); p0[2] = f2bf(f0.z); p0[3] = f2bf(f0.w);
            p0[4] = f2bf(f1.x); p0[5] = f2bf(f1.y); p0[6] = f2bf(f1.z); p0[7] = f2bf(f1.w);
            p1[0] = f2bf(f2.x); p1[1] = f2bf(f2.y); p1[2] = f2bf(f2.z); p1[3] = f2bf(f2.w);
            p1[4] = f2bf(f3.x); p1[5] = f2bf(f3.y); p1[6] = f2bf(f3.z); p1[7] = f2bf(f3.w);
            *(u16x8*)&Bs[srow][scol] = p0;
            *(u16x8*)&Bs[srow][scol + 8] = p1;
        }
        __syncthreads();

        bf16x8 af[4], bfr[4];
        #pragma unroll
        for (int mt = 0; mt < 4; ++mt)
            af[mt] = *(const bf16x8*)&As[wm * 64 + mt * 16 + l15][l4 * 8];
        #pragma unroll
        for (int nt = 0; nt < 4; ++nt)
            bfr[nt] = *(const bf16x8*)&Bs[wn * 64 + nt * 16 + l15][l4 * 8];
        #pragma unroll
        for (int mt = 0; mt < 4; ++mt)
            #pragma unroll
            for (int nt = 0; nt < 4; ++nt)
                acc[mt][nt] = __builtin_amdgcn_mfma_f32_16x16x32_bf16(af[mt], bfr[nt], acc[mt][nt], 0, 0, 0);
        __syncthreads();
    }

    const float scale = 1.0f / 32.0f;   // 1/sqrt(D)
    #pragma unroll
    for (int mt = 0; mt < 4; ++mt) {
        #pragma unroll
        for (int nt = 0; nt < 4; ++nt) {
            const int n = n0 + wn * 64 + nt * 16 + l15;
            const int h = n >> 6, dh = n & 63;
            #pragma unroll
            for (int r = 0; r < 4; ++r) {
                const int m = m0 + wm * 64 + mt * 16 + l4 * 4 + r;
                const int b = m >> 11, t = m & 2047;
                qb[(((size_t)b * H_ + h) * T_ + t) * DH_ + dh] = f2bf(acc[mt][nt][r] * scale);
            }
        }
    }
}

// ---------------------------------------------------------------------------
// Kernel 2: MFMA flash attention + residual.
// Block = 256 thr (4 waves), one (b,h,128-row q-tile). Wave w owns rows
// w*32..w*32+32. Q frags live in registers. 64-key K/V LDS tiles. P goes
// C-layout -> LDS -> A-layout (wave-private rows, no extra barrier).
// ---------------------------------------------------------------------------
__global__ __launch_bounds__(256) void attn_kernel(
    const unsigned short* __restrict__ qb,   // [B,H,T,DH] bf16, pre-scaled
    const unsigned short* __restrict__ kb,   // [B,H,T,DH] bf16
    const unsigned short* __restrict__ vt,   // [B,H,DH,T] bf16
    const float* __restrict__ xg,            // [B,T,D] fp32
    float* __restrict__ out)                 // [B,T,D] fp32
{
    __shared__ unsigned short Ks[64][72];    // +8 pad: 2-way max
    __shared__ unsigned short Vs[64][72];    // V^T tile: [dh][key]
    __shared__ unsigned short Ps[128][72];

    const int tid = threadIdx.x;
    const int lane = tid & 63;
    const int w = tid >> 6;
    const int l15 = lane & 15, l4 = lane >> 4;
    const int qt = 15 - blockIdx.x;          // heavy tiles dispatch first
    const int h = blockIdx.y, b = blockIdx.z;
    const int q0 = qt * 128;
    const size_t bh = (size_t)b * H_ + h;

    // Q fragments in registers for the whole kernel
    bf16x8 qf[2][2];
    #pragma unroll
    for (int mt = 0; mt < 2; ++mt)
        #pragma unroll
        for (int kc = 0; kc < 2; ++kc)
            qf[mt][kc] = *(const bf16x8*)(qb + (bh * T_ + q0 + w * 32 + mt * 16 + l15) * DH_ + kc * 32 + l4 * 8);

    f32x4 o_acc[2][4] = {};
    float m_i[2][4], l_i[2][4];
    #pragma unroll
    for (int mt = 0; mt < 2; ++mt)
        #pragma unroll
        for (int r = 0; r < 4; ++r) { m_i[mt][r] = -INFINITY; l_i[mt][r] = 0.0f; }

    const int srow = tid >> 2;           // 0..63
    const int scol = (tid & 3) * 16;     // 0,16,32,48

    for (int j0 = 0; j0 < q0 + 128; j0 += 64) {
        // stage K tile [key][dh] and V^T tile [dh][key]
        {
            const unsigned short* gk = kb + (bh * T_ + j0 + srow) * DH_ + scol;
            const uint4 k0v = *(const uint4*)gk;
            const uint4 k1v = *(const uint4*)(gk + 8);
            *(uint4*)&Ks[srow][scol] = k0v;
            *(uint4*)&Ks[srow][scol + 8] = k1v;
            const unsigned short* gv = vt + (bh * DH_ + srow) * T_ + j0 + scol;
            const uint4 v0v = *(const uint4*)gv;
            const uint4 v1v = *(const uint4*)(gv + 8);
            *(uint4*)&Vs[srow][scol] = v0v;
            *(uint4*)&Vs[srow][scol + 8] = v1v;
        }
        __syncthreads();

        // S = Q K^T  (q pre-scaled by 1/32)
        f32x4 s[2][4] = {};
        #pragma unroll
        for (int kc = 0; kc < 2; ++kc) {
            bf16x8 kf[4];
            #pragma unroll
            for (int nt = 0; nt < 4; ++nt)
                kf[nt] = *(const bf16x8*)&Ks[nt * 16 + l15][kc * 32 + l4 * 8];
            #pragma unroll
            for (int mt = 0; mt < 2; ++mt)
                #pragma unroll
                for (int nt = 0; nt < 4; ++nt)
                    s[mt][nt] = __builtin_amdgcn_mfma_f32_16x16x32_bf16(qf[mt][kc], kf[nt], s[mt][nt], 0, 0, 0);
        }

        // causal mask — only the last two k-tiles can be partial
        if (j0 + 64 > q0) {
            #pragma unroll
            for (int mt = 0; mt < 2; ++mt)
                #pragma unroll
                for (int nt = 0; nt < 4; ++nt)
                    #pragma unroll
                    for (int r = 0; r < 4; ++r) {
                        const int row = q0 + w * 32 + mt * 16 + l4 * 4 + r;
                        const int key = j0 + nt * 16 + l15;
                        if (key > row) s[mt][nt][r] = -INFINITY;
                    }
        }

        // online softmax (rows spread over 16-lane groups), write P -> LDS
        #pragma unroll
        for (int mt = 0; mt < 2; ++mt) {
            #pragma unroll
            for (int r = 0; r < 4; ++r) {
                float rm = fmaxf(fmaxf(s[mt][0][r], s[mt][1][r]), fmaxf(s[mt][2][r], s[mt][3][r]));
                #pragma unroll
                for (int off = 1; off < 16; off <<= 1)
                    rm = fmaxf(rm, __shfl_xor(rm, off));
                const float mn = fmaxf(m_i[mt][r], rm);
                const float alpha = __expf(m_i[mt][r] - mn);
                float rs = 0.0f;
                #pragma unroll
                for (int nt = 0; nt < 4; ++nt) {
                    const float p = __expf(s[mt][nt][r] - mn);
                    s[mt][nt][r] = p;
                    rs += p;
                }
                #pragma unroll
                for (int off = 1; off < 16; off <<= 1)
                    rs += __shfl_xor(rs, off);
                l_i[mt][r] = l_i[mt][r] * alpha + rs;
                m_i[mt][r] = mn;
                #pragma unroll
                for (int nt = 0; nt < 4; ++nt) {
                    o_acc[mt][nt][r] *= alpha;
                    Ps[w * 32 + mt * 16 + l4 * 4 + r][nt * 16 + l15] = f2bf(s[mt][nt][r]);
                }
            }
        }

        // O += P V   (A = P from LDS, B = V^T from LDS)
        #pragma unroll
        for (int kc = 0; kc < 2; ++kc) {
            bf16x8 pf[2], vf[4];
            #pragma unroll
            for (int mt = 0; mt < 2; ++mt)
                pf[mt] = *(const bf16x8*)&Ps[w * 32 + mt * 16 + l15][kc * 32 + l4 * 8];
            #pragma unroll
            for (int nt = 0; nt < 4; ++nt)
                vf[nt] = *(const bf16x8*)&Vs[nt * 16 + l15][kc * 32 + l4 * 8];
            #pragma unroll
            for (int mt = 0; mt < 2; ++mt)
                #pragma unroll
                for (int nt = 0; nt < 4; ++nt)
                    o_acc[mt][nt] = __builtin_amdgcn_mfma_f32_16x16x32_bf16(pf[mt], vf[nt], o_acc[mt][nt], 0, 0, 0);
        }
        __syncthreads();
    }

    // epilogue: out = x + O / l
    #pragma unroll
    for (int mt = 0; mt < 2; ++mt) {
        #pragma unroll
        for (int r = 0; r < 4; ++r) {
            const int row = q0 + w * 32 + mt * 16 + l4 * 4 + r;
            const float inv = 1.0f / l_i[mt][r];
            #pragma unroll
            for (int nt = 0; nt < 4; ++nt) {
                const int d = h * DH_ + nt * 16 + l15;
                const size_t off = ((size_t)b * T_ + row) * D_ + d;
                out[off] = xg[off] + o_acc[mt][nt][r] * inv;
            }
        }
    }
}

extern "C" void kernel_launch(void* const* d_in, const int* in_sizes, int n_in,
                              void* d_out, int out_size, void* d_ws, size_t ws_size,
                              hipStream_t stream) {
    const float* x  = (const float*)d_in[0];
    const float* k  = (const float*)d_in[1];
    const float* v  = (const float*)d_in[2];
    const float* Wq = (const float*)d_in[3];
    float* out = (float*)d_out;

    const size_t NE = (size_t)B_ * H_ * T_ * DH_;   // 4M elements
    unsigned short* kb = (unsigned short*)d_ws;     // 8 MB
    unsigned short* vt = kb + NE;                   // 8 MB
    unsigned short* qb = vt + NE;                   // 8 MB

    convk_kernel<<<NE / (256 * 8), 256, 0, stream>>>(k, kb);
    transv_kernel<<<dim3(T_ / 64, H_, B_), 256, 0, stream>>>(v, vt);
    qproj_kernel<<<dim3(D_ / 128, (B_ * T_) / 128), 256, 0, stream>>>(x, Wq, qb);
    attn_kernel<<<dim3(T_ / 128, H_, B_), 256, 0, stream>>>(qb, kb, vt, x, out);
}

// Round 4
// 205.348 us; speedup vs baseline: 5.1458x; 1.3366x over previous
//
#include <hip/hip_runtime.h>
#include <hip/hip_bf16.h>

#define B_ 2
#define T_ 2048
#define D_ 1024
#define H_ 16
#define DH_ 64

typedef __attribute__((ext_vector_type(8))) short bf16x8;
typedef __attribute__((ext_vector_type(4))) float f32x4;
typedef __attribute__((ext_vector_type(8))) unsigned short u16x8;

__device__ __forceinline__ unsigned short f2bf(float f) {
    unsigned int u = __float_as_uint(f);
    return (unsigned short)((u + 0x7FFFu + ((u >> 16) & 1u)) >> 16);
}

// ---------------------------------------------------------------------------
// Prepass (single launch): blocks [0,2048) convert k fp32->bf16;
// blocks [2048,3072) transpose+convert v[b,h,t,dh] -> vt[b,h,dh,t] bf16.
// ---------------------------------------------------------------------------
__global__ __launch_bounds__(256) void prep_kernel(const float* __restrict__ k,
                                                   const float* __restrict__ v,
                                                   unsigned short* __restrict__ kb,
                                                   unsigned short* __restrict__ vt) {
    __shared__ float Ts[64][65];
    const int tid = threadIdx.x;
    const int bi = blockIdx.x;
    if (bi < 2048) {                       // k conversion: 4M elems, 8/thread
        const size_t i = ((size_t)bi * 256 + tid) * 8;
        const float4 a = *(const float4*)(k + i);
        const float4 b = *(const float4*)(k + i + 4);
        u16x8 o;
        o[0] = f2bf(a.x); o[1] = f2bf(a.y); o[2] = f2bf(a.z); o[3] = f2bf(a.w);
        o[4] = f2bf(b.x); o[5] = f2bf(b.y); o[6] = f2bf(b.z); o[7] = f2bf(b.w);
        *(u16x8*)(kb + i) = o;
        return;
    }
    const int idx = bi - 2048;             // transv: 1024 tiles of 64x64
    const int t0 = (idx & 31) * 64;
    const int hb = idx >> 5;
    const size_t bh = (size_t)(hb >> 4) * H_ + (hb & 15);
    #pragma unroll
    for (int u = 0; u < 4; ++u) {
        const int tr = u * 16 + (tid >> 4);
        const int dc = (tid & 15) * 4;
        const float4 r = *(const float4*)(v + (bh * T_ + t0 + tr) * DH_ + dc);
        Ts[tr][dc + 0] = r.x; Ts[tr][dc + 1] = r.y;
        Ts[tr][dc + 2] = r.z; Ts[tr][dc + 3] = r.w;
    }
    __syncthreads();
    #pragma unroll
    for (int u = 0; u < 4; ++u) {
        const int dh = u * 16 + (tid >> 4);
        const int tc = (tid & 15) * 4;
        ushort4 o;
        o.x = f2bf(Ts[tc + 0][dh]); o.y = f2bf(Ts[tc + 1][dh]);
        o.z = f2bf(Ts[tc + 2][dh]); o.w = f2bf(Ts[tc + 3][dh]);
        *(ushort4*)(vt + (bh * DH_ + dh) * T_ + t0 + tc) = o;
    }
}

// ---------------------------------------------------------------------------
// Kernel 1: qb = bf16( (x @ Wq^T) / 32 ), layout [B,H,T,DH]
// 64(M)x128(N) tile, BK=32, 256 thr (4 waves 2x2, each 32x64), 512 blocks.
// fp32 global loads converted to bf16 during LDS staging.
// ---------------------------------------------------------------------------
__global__ __launch_bounds__(256) void qproj_kernel(const float* __restrict__ x,
                                                    const float* __restrict__ Wq,
                                                    unsigned short* __restrict__ qb) {
    __shared__ unsigned short As[64][40];    // +8 pad
    __shared__ unsigned short Bs[128][40];

    const int tid = threadIdx.x;
    const int lane = tid & 63;
    const int w = tid >> 6;
    const int wm = w >> 1, wn = w & 1;
    const int l15 = lane & 15, l4 = lane >> 4;
    const int m0 = blockIdx.y * 64, n0 = blockIdx.x * 128;

    f32x4 acc[2][4] = {};

    const int arow = tid >> 2, acol = (tid & 3) * 8;     // As: 8 elems/thread
    const int brow = tid >> 1, bcol = (tid & 1) * 16;    // Bs: 16 elems/thread

    for (int k0 = 0; k0 < D_; k0 += 32) {
        {
            const float* g = x + (size_t)(m0 + arow) * D_ + k0 + acol;
            const float4 f0 = *(const float4*)(g);
            const float4 f1 = *(const float4*)(g + 4);
            u16x8 p;
            p[0] = f2bf(f0.x); p[1] = f2bf(f0.y); p[2] = f2bf(f0.z); p[3] = f2bf(f0.w);
            p[4] = f2bf(f1.x); p[5] = f2bf(f1.y); p[6] = f2bf(f1.z); p[7] = f2bf(f1.w);
            *(u16x8*)&As[arow][acol] = p;
        }
        {
            const float* g = Wq + (size_t)(brow) * D_ + n0 * 0 + k0 + bcol;  // brow is row in [0,128)
            const float* gw = Wq + (size_t)(n0 + brow) * D_ + k0 + bcol;
            (void)g;
            const float4 f0 = *(const float4*)(gw);
            const float4 f1 = *(const float4*)(gw + 4);
            const float4 f2 = *(const float4*)(gw + 8);
            const float4 f3 = *(const float4*)(gw + 12);
            u16x8 p0, p1;
            p0[0] = f2bf(f0.x); p0[1] = f2bf(f0.y); p0[2] = f2bf(f0.z); p0[3] = f2bf(f0.w);
            p0[4] = f2bf(f1.x); p0[5] = f2bf(f1.y); p0[6] = f2bf(f1.z); p0[7] = f2bf(f1.w);
            p1[0] = f2bf(f2.x); p1[1] = f2bf(f2.y); p1[2] = f2bf(f2.z); p1[3] = f2bf(f2.w);
            p1[4] = f2bf(f3.x); p1[5] = f2bf(f3.y); p1[6] = f2bf(f3.z); p1[7] = f2bf(f3.w);
            *(u16x8*)&Bs[brow][bcol] = p0;
            *(u16x8*)&Bs[brow][bcol + 8] = p1;
        }
        __syncthreads();

        bf16x8 af[2], bfr[4];
        #pragma unroll
        for (int mt = 0; mt < 2; ++mt)
            af[mt] = *(const bf16x8*)&As[wm * 32 + mt * 16 + l15][l4 * 8];
        #pragma unroll
        for (int nt = 0; nt < 4; ++nt)
            bfr[nt] = *(const bf16x8*)&Bs[wn * 64 + nt * 16 + l15][l4 * 8];
        #pragma unroll
        for (int mt = 0; mt < 2; ++mt)
            #pragma unroll
            for (int nt = 0; nt < 4; ++nt)
                acc[mt][nt] = __builtin_amdgcn_mfma_f32_16x16x32_bf16(af[mt], bfr[nt], acc[mt][nt], 0, 0, 0);
        __syncthreads();
    }

    const float scale = 1.0f / 32.0f;   // 1/sqrt(D)
    #pragma unroll
    for (int mt = 0; mt < 2; ++mt) {
        #pragma unroll
        for (int nt = 0; nt < 4; ++nt) {
            const int n = n0 + wn * 64 + nt * 16 + l15;
            const int h = n >> 6, dh = n & 63;
            #pragma unroll
            for (int r = 0; r < 4; ++r) {
                const int m = m0 + wm * 32 + mt * 16 + l4 * 4 + r;
                const int b = m >> 11, t = m & 2047;
                qb[(((size_t)b * H_ + h) * T_ + t) * DH_ + dh] = f2bf(acc[mt][nt][r] * scale);
            }
        }
    }
}

// ---------------------------------------------------------------------------
// Kernel 2: MFMA flash attention + residual.
// 64-row Q-tile per block, 4 waves each owning 16 rows. 1024 blocks,
// heavy tiles (qt=31) dispatched first. Q frags in registers. 64-key K/V
// LDS tiles (+8 pad). P: C-layout -> wave-private LDS rows -> A-layout.
// ---------------------------------------------------------------------------
__global__ __launch_bounds__(256) void attn_kernel(
    const unsigned short* __restrict__ qb,   // [B,H,T,DH] bf16, pre-scaled
    const unsigned short* __restrict__ kb,   // [B,H,T,DH] bf16
    const unsigned short* __restrict__ vt,   // [B,H,DH,T] bf16
    const float* __restrict__ xg,            // [B,T,D] fp32
    float* __restrict__ out)                 // [B,T,D] fp32
{
    __shared__ unsigned short Ks[64][72];    // [key][dh]
    __shared__ unsigned short Vs[64][72];    // [dh][key]
    __shared__ unsigned short Ps[64][72];    // [qrow][key]

    const int tid = threadIdx.x;
    const int lane = tid & 63;
    const int w = tid >> 6;
    const int l15 = lane & 15, l4 = lane >> 4;
    const int bi = blockIdx.x;
    const int qt = 31 - (bi >> 5);           // heavy q-tiles dispatch first
    const int hb = bi & 31;
    const int h = hb & 15, b = hb >> 4;
    const int q0 = qt * 64;
    const size_t bh = (size_t)b * H_ + h;

    // Q fragments in registers for the whole kernel (rows w*16 .. w*16+15)
    bf16x8 qf[2];
    #pragma unroll
    for (int kc = 0; kc < 2; ++kc)
        qf[kc] = *(const bf16x8*)(qb + (bh * T_ + q0 + w * 16 + l15) * DH_ + kc * 32 + l4 * 8);

    f32x4 o_acc[4] = {};
    float m_i[4], l_i[4];
    #pragma unroll
    for (int r = 0; r < 4; ++r) { m_i[r] = -INFINITY; l_i[r] = 0.0f; }

    const int srow = tid >> 2;           // 0..63
    const int scol = (tid & 3) * 16;     // 0,16,32,48

    for (int j0 = 0; j0 <= q0; j0 += 64) {
        // stage K tile [key][dh] and V^T tile [dh][key]
        {
            const unsigned short* gk = kb + (bh * T_ + j0 + srow) * DH_ + scol;
            const uint4 k0v = *(const uint4*)gk;
            const uint4 k1v = *(const uint4*)(gk + 8);
            *(uint4*)&Ks[srow][scol] = k0v;
            *(uint4*)&Ks[srow][scol + 8] = k1v;
            const unsigned short* gv = vt + (bh * DH_ + srow) * T_ + j0 + scol;
            const uint4 v0v = *(const uint4*)gv;
            const uint4 v1v = *(const uint4*)(gv + 8);
            *(uint4*)&Vs[srow][scol] = v0v;
            *(uint4*)&Vs[srow][scol + 8] = v1v;
        }
        __syncthreads();

        // S = Q K^T  (q pre-scaled by 1/32); s[nt]: key=nt*16+l15, row=l4*4+r
        f32x4 s[4] = {};
        #pragma unroll
        for (int kc = 0; kc < 2; ++kc) {
            bf16x8 kf[4];
            #pragma unroll
            for (int nt = 0; nt < 4; ++nt)
                kf[nt] = *(const bf16x8*)&Ks[nt * 16 + l15][kc * 32 + l4 * 8];
            #pragma unroll
            for (int nt = 0; nt < 4; ++nt)
                s[nt] = __builtin_amdgcn_mfma_f32_16x16x32_bf16(qf[kc], kf[nt], s[nt], 0, 0, 0);
        }

        // causal mask — only the diagonal tile is partial
        if (j0 == q0) {
            #pragma unroll
            for (int nt = 0; nt < 4; ++nt)
                #pragma unroll
                for (int r = 0; r < 4; ++r) {
                    const int row = w * 16 + l4 * 4 + r;
                    const int key = nt * 16 + l15;
                    if (key > row) s[nt][r] = -INFINITY;
                }
        }

        // online softmax (row spread over nt regs + 16 lanes); P -> LDS bf16
        #pragma unroll
        for (int r = 0; r < 4; ++r) {
            float rm = fmaxf(fmaxf(s[0][r], s[1][r]), fmaxf(s[2][r], s[3][r]));
            #pragma unroll
            for (int off = 1; off < 16; off <<= 1)
                rm = fmaxf(rm, __shfl_xor(rm, off));
            const float mn = fmaxf(m_i[r], rm);
            const float alpha = __expf(m_i[r] - mn);
            float rs = 0.0f;
            #pragma unroll
            for (int nt = 0; nt < 4; ++nt) {
                const float p = __expf(s[nt][r] - mn);
                s[nt][r] = p;
                rs += p;
            }
            #pragma unroll
            for (int off = 1; off < 16; off <<= 1)
                rs += __shfl_xor(rs, off);
            l_i[r] = l_i[r] * alpha + rs;
            m_i[r] = mn;
            #pragma unroll
            for (int nt = 0; nt < 4; ++nt) {
                o_acc[nt][r] *= alpha;
                Ps[w * 16 + l4 * 4 + r][nt * 16 + l15] = f2bf(s[nt][r]);
            }
        }
        // Ps rows are wave-private: no barrier needed before reading back

        // O += P V   (A = P from LDS, B = V^T from LDS)
        #pragma unroll
        for (int kc = 0; kc < 2; ++kc) {
            bf16x8 pf, vf[4];
            pf = *(const bf16x8*)&Ps[w * 16 + l15][kc * 32 + l4 * 8];
            #pragma unroll
            for (int nt = 0; nt < 4; ++nt)
                vf[nt] = *(const bf16x8*)&Vs[nt * 16 + l15][kc * 32 + l4 * 8];
            #pragma unroll
            for (int nt = 0; nt < 4; ++nt)
                o_acc[nt] = __builtin_amdgcn_mfma_f32_16x16x32_bf16(pf, vf[nt], o_acc[nt], 0, 0, 0);
        }
        __syncthreads();
    }

    // epilogue: out = x + O / l
    #pragma unroll
    for (int r = 0; r < 4; ++r) {
        const int row = q0 + w * 16 + l4 * 4 + r;
        const float inv = 1.0f / l_i[r];
        #pragma unroll
        for (int nt = 0; nt < 4; ++nt) {
            const int d = h * DH_ + nt * 16 + l15;
            const size_t off = ((size_t)b * T_ + row) * D_ + d;
            out[off] = xg[off] + o_acc[nt][r] * inv;
        }
    }
}

extern "C" void kernel_launch(void* const* d_in, const int* in_sizes, int n_in,
                              void* d_out, int out_size, void* d_ws, size_t ws_size,
                              hipStream_t stream) {
    const float* x  = (const float*)d_in[0];
    const float* k  = (const float*)d_in[1];
    const float* v  = (const float*)d_in[2];
    const float* Wq = (const float*)d_in[3];
    float* out = (float*)d_out;

    const size_t NE = (size_t)B_ * H_ * T_ * DH_;   // 4M elements
    unsigned short* kb = (unsigned short*)d_ws;     // 8 MB
    unsigned short* vt = kb + NE;                   // 8 MB
    unsigned short* qb = vt + NE;                   // 8 MB

    prep_kernel<<<3072, 256, 0, stream>>>(k, v, kb, vt);
    qproj_kernel<<<dim3(D_ / 128, (B_ * T_) / 64), 256, 0, stream>>>(x, Wq, qb);
    attn_kernel<<<1024, 256, 0, stream>>>(qb, kb, vt, x, out);
}

// Round 6
// 172.290 us; speedup vs baseline: 6.1331x; 1.1919x over previous
//
#include <hip/hip_runtime.h>
#include <hip/hip_bf16.h>

#define B_ 2
#define T_ 2048
#define D_ 1024
#define H_ 16
#define DH_ 64

typedef __attribute__((ext_vector_type(8))) short bf16x8;
typedef __attribute__((ext_vector_type(4))) short bf16x4;
typedef __attribute__((ext_vector_type(4))) float f32x4;
typedef __attribute__((ext_vector_type(8))) unsigned short u16x8;

__device__ __forceinline__ unsigned short f2bf(float f) {   // RNE fp32->bf16
    unsigned int u = __float_as_uint(f);
    return (unsigned short)((u + 0x7FFFu + ((u >> 16) & 1u)) >> 16);
}

__device__ __forceinline__ void pack8(const float4& a, const float4& b, u16x8& o) {
    o[0] = f2bf(a.x); o[1] = f2bf(a.y); o[2] = f2bf(a.z); o[3] = f2bf(a.w);
    o[4] = f2bf(b.x); o[5] = f2bf(b.y); o[6] = f2bf(b.z); o[7] = f2bf(b.w);
}

// K=16 bf16 MFMA; guard so the host pass never needs the builtin.
__device__ __forceinline__ f32x4 mfma16(bf16x4 a, bf16x4 b, f32x4 c) {
#if defined(__HIP_DEVICE_COMPILE__)
    return __builtin_amdgcn_mfma_f32_16x16x16bf16_1k(a, b, c, 0, 0, 0);
#else
    return c;   // host pass: never executed
#endif
}

// ---------------------------------------------------------------------------
// Launch 1 (fused, all-independent blocks). Heavy qproj tiles dispatch FIRST:
//   [0,1024)   : qproj 64x64 tile, BK=64 -> qb bf16 [B,H,T,DH], pre-scaled
//   [1024,1536): k fp32 -> kb bf16 (32 elems/thread)
//   [1536,2560): v[b,h,t,dh] -> vt[b,h,dh,t] bf16 (64x64 LDS transpose)
// ---------------------------------------------------------------------------
__global__ __launch_bounds__(256) void fused_prep_qproj(
    const float* __restrict__ k, const float* __restrict__ v,
    const float* __restrict__ x, const float* __restrict__ Wq,
    unsigned short* __restrict__ kb, unsigned short* __restrict__ vt,
    unsigned short* __restrict__ qb)
{
    __shared__ __align__(16) char lds_raw[18432];
    const int tid = threadIdx.x;
    const int bi = blockIdx.x;

    if (bi >= 1024 && bi < 1536) {        // ---- k conversion ----
        const int idx = bi - 1024;
        const float* src = k + ((size_t)idx * 256 + tid) * 32;
        unsigned short* dst = kb + ((size_t)idx * 256 + tid) * 32;
        #pragma unroll
        for (int u = 0; u < 4; ++u) {
            const float4 a = *(const float4*)(src + u * 8);
            const float4 b = *(const float4*)(src + u * 8 + 4);
            u16x8 o; pack8(a, b, o);
            *(u16x8*)(dst + u * 8) = o;
        }
        return;
    }

    if (bi >= 1536) {                     // ---- v transpose+convert ----
        float (*Ts)[65] = (float(*)[65])lds_raw;
        const int idx = bi - 1536;
        const int t0 = (idx & 31) * 64;
        const int hb = idx >> 5;
        const size_t bh = (size_t)(hb >> 4) * H_ + (hb & 15);
        #pragma unroll
        for (int u = 0; u < 4; ++u) {
            const int tr = u * 16 + (tid >> 4);
            const int dc = (tid & 15) * 4;
            const float4 r = *(const float4*)(v + (bh * T_ + t0 + tr) * DH_ + dc);
            Ts[tr][dc + 0] = r.x; Ts[tr][dc + 1] = r.y;
            Ts[tr][dc + 2] = r.z; Ts[tr][dc + 3] = r.w;
        }
        __syncthreads();
        #pragma unroll
        for (int u = 0; u < 4; ++u) {
            const int dh = u * 16 + (tid >> 4);
            const int tc = (tid & 15) * 4;
            ushort4 o;
            o.x = f2bf(Ts[tc + 0][dh]); o.y = f2bf(Ts[tc + 1][dh]);
            o.z = f2bf(Ts[tc + 2][dh]); o.w = f2bf(Ts[tc + 3][dh]);
            *(ushort4*)(vt + (bh * DH_ + dh) * T_ + t0 + tc) = o;
        }
        return;
    }

    // ---- qproj: 64x64 tile, BK=64, 4 waves each 16 rows x 64 cols ----
    unsigned short (*As)[72] = (unsigned short(*)[72])lds_raw;
    unsigned short (*Bs)[72] = (unsigned short(*)[72])(lds_raw + 9216);

    const int m0 = (bi >> 4) * 64;        // 64 m-tiles over B*T
    const int h  = bi & 15;               // n-tile == head
    const int n0 = h * 64;

    const int lane = tid & 63;
    const int w = tid >> 6;
    const int l15 = lane & 15, l4 = lane >> 4;
    const int row = tid >> 2;             // staging: 0..63
    const int c   = (tid & 3) * 16;       // staging col

    f32x4 acc[4] = {};

    for (int k0 = 0; k0 < D_; k0 += 64) {
        {
            const float* g = x + (size_t)(m0 + row) * D_ + k0 + c;
            u16x8 p0, p1;
            pack8(*(const float4*)(g), *(const float4*)(g + 4), p0);
            pack8(*(const float4*)(g + 8), *(const float4*)(g + 12), p1);
            *(u16x8*)&As[row][c] = p0;
            *(u16x8*)&As[row][c + 8] = p1;
        }
        {
            const float* g = Wq + (size_t)(n0 + row) * D_ + k0 + c;
            u16x8 p0, p1;
            pack8(*(const float4*)(g), *(const float4*)(g + 4), p0);
            pack8(*(const float4*)(g + 8), *(const float4*)(g + 12), p1);
            *(u16x8*)&Bs[row][c] = p0;
            *(u16x8*)&Bs[row][c + 8] = p1;
        }
        __syncthreads();

        #pragma unroll
        for (int kc = 0; kc < 2; ++kc) {
            const bf16x8 af = *(const bf16x8*)&As[w * 16 + l15][kc * 32 + l4 * 8];
            #pragma unroll
            for (int nt = 0; nt < 4; ++nt) {
                const bf16x8 bfr = *(const bf16x8*)&Bs[nt * 16 + l15][kc * 32 + l4 * 8];
                acc[nt] = __builtin_amdgcn_mfma_f32_16x16x32_bf16(af, bfr, acc[nt], 0, 0, 0);
            }
        }
        __syncthreads();
    }

    const float scale = 1.0f / 32.0f;     // 1/sqrt(D)
    #pragma unroll
    for (int nt = 0; nt < 4; ++nt) {
        const int dh = nt * 16 + l15;
        #pragma unroll
        for (int r = 0; r < 4; ++r) {
            const int m = m0 + w * 16 + l4 * 4 + r;
            const int b = m >> 11, t = m & 2047;
            qb[(((size_t)b * H_ + h) * T_ + t) * DH_ + dh] = f2bf(acc[nt][r] * scale);
        }
    }
}

// ---------------------------------------------------------------------------
// Launch 2: transposed-S MFMA flash attention + residual.
// 64 q-rows/block (4 waves x 16 rows), 1024 blocks, heavy tiles first.
// S^T = K*Q^T  (col = qrow -> softmax state is one scalar/lane, 2 shfls).
// P^T stays in registers: S^T C-layout (row=l4*4+r) == B-operand k-layout of
// the K=16 MFMA (k=l4*4+j). O^T = V^T * P^T. Double-buffered K/V, 1 barrier.
// ---------------------------------------------------------------------------
__global__ __launch_bounds__(256, 4) void attn_kernel(
    const unsigned short* __restrict__ qb,   // [B,H,T,DH] bf16, pre-scaled
    const unsigned short* __restrict__ kb,   // [B,H,T,DH] bf16
    const unsigned short* __restrict__ vt,   // [B,H,DH,T] bf16
    const float* __restrict__ xg,            // [B,T,D] fp32
    float* __restrict__ out)                 // [B,T,D] fp32
{
    __shared__ unsigned short Ks[2][64][72];   // [key][dh]
    __shared__ unsigned short Vs[2][64][72];   // [dh][key]

    const int tid = threadIdx.x;
    const int lane = tid & 63;
    const int w = tid >> 6;
    const int l15 = lane & 15, l4 = lane >> 4;
    const int bi = blockIdx.x;
    const int qt = 31 - (bi >> 5);           // heavy q-tiles dispatch first
    const int hb = bi & 31;
    const int h = hb & 15, b = hb >> 4;
    const int q0 = qt * 64;
    const size_t bh = (size_t)b * H_ + h;

    // Q fragments (B-operand: lane l15 = qrow, k = dh = kc*32 + l4*8+j)
    bf16x8 qf[2];
    #pragma unroll
    for (int kc = 0; kc < 2; ++kc)
        qf[kc] = *(const bf16x8*)(qb + (bh * T_ + q0 + w * 16 + l15) * DH_ + kc * 32 + l4 * 8);

    f32x4 o_acc[4] = {};                     // O^T: dh = mt*16+l4*4+r, qrow = l15
    float m_i = -INFINITY, l_i = 0.0f;       // one qrow per lane

    const int srow = tid >> 2;               // staging 0..63
    const int scol = (tid & 3) * 16;

    // stage tile j0=0 into buffer 0
    {
        const unsigned short* gk = kb + (bh * T_ + srow) * DH_ + scol;
        *(uint4*)&Ks[0][srow][scol] = *(const uint4*)gk;
        *(uint4*)&Ks[0][srow][scol + 8] = *(const uint4*)(gk + 8);
        const unsigned short* gv = vt + (bh * DH_ + srow) * T_ + scol;
        *(uint4*)&Vs[0][srow][scol] = *(const uint4*)gv;
        *(uint4*)&Vs[0][srow][scol + 8] = *(const uint4*)(gv + 8);
    }
    __syncthreads();

    int p = 0;
    for (int j0 = 0; j0 <= q0; j0 += 64) {
        // prefetch next tile into registers (valid-but-discarded addr on last)
        const int jn = (j0 + 64 <= q0) ? j0 + 64 : 0;
        uint4 kr0, kr1, vr0, vr1;
        {
            const unsigned short* gk = kb + (bh * T_ + jn + srow) * DH_ + scol;
            kr0 = *(const uint4*)gk;
            kr1 = *(const uint4*)(gk + 8);
            const unsigned short* gv = vt + (bh * DH_ + srow) * T_ + jn + scol;
            vr0 = *(const uint4*)gv;
            vr1 = *(const uint4*)(gv + 8);
        }

        // S^T = K * Q^T : st[nt] keys nt*16 + l4*4+r, qrow = w*16+l15
        f32x4 st[4] = {};
        #pragma unroll
        for (int kc = 0; kc < 2; ++kc) {
            #pragma unroll
            for (int nt = 0; nt < 4; ++nt) {
                const bf16x8 kf = *(const bf16x8*)&Ks[p][nt * 16 + l15][kc * 32 + l4 * 8];
                st[nt] = __builtin_amdgcn_mfma_f32_16x16x32_bf16(kf, qf[kc], st[nt], 0, 0, 0);
            }
        }

        // causal mask (diagonal tile only)
        if (j0 == q0) {
            const int thr = w * 16 + l15 - l4 * 4;   // mask if nt*16+r > thr
            #pragma unroll
            for (int nt = 0; nt < 4; ++nt)
                #pragma unroll
                for (int r = 0; r < 4; ++r)
                    if (nt * 16 + r > thr) st[nt][r] = -INFINITY;
        }

        // online softmax: 16 in-lane values + 2-shfl butterfly over l4
        float rm = -INFINITY;
        #pragma unroll
        for (int nt = 0; nt < 4; ++nt)
            #pragma unroll
            for (int r = 0; r < 4; ++r) rm = fmaxf(rm, st[nt][r]);
        rm = fmaxf(rm, __shfl_xor(rm, 16));
        rm = fmaxf(rm, __shfl_xor(rm, 32));
        const float mn = fmaxf(m_i, rm);
        const float alpha = __expf(m_i - mn);
        float rs = 0.0f;
        #pragma unroll
        for (int nt = 0; nt < 4; ++nt)
            #pragma unroll
            for (int r = 0; r < 4; ++r) {
                const float pv = __expf(st[nt][r] - mn);
                st[nt][r] = pv;
                rs += pv;
            }
        rs += __shfl_xor(rs, 16);
        rs += __shfl_xor(rs, 32);
        l_i = l_i * alpha + rs;
        m_i = mn;
        #pragma unroll
        for (int mt = 0; mt < 4; ++mt)
            #pragma unroll
            for (int r = 0; r < 4; ++r) o_acc[mt][r] *= alpha;

        // pack P^T into K=16 B-frags (v_perm truncation, 2 vals/op)
        bf16x4 pf[4];
        #pragma unroll
        for (int nt = 0; nt < 4; ++nt) {
            union { unsigned int u[2]; bf16x4 s; } cv;
            cv.u[0] = __builtin_amdgcn_perm(__float_as_uint(st[nt][1]),
                                            __float_as_uint(st[nt][0]), 0x07060302u);
            cv.u[1] = __builtin_amdgcn_perm(__float_as_uint(st[nt][3]),
                                            __float_as_uint(st[nt][2]), 0x07060302u);
            pf[nt] = cv.s;
        }

        // O^T += V^T * P^T  (A = V^T from LDS, B = P^T in registers)
        #pragma unroll
        for (int c = 0; c < 4; ++c) {
            #pragma unroll
            for (int mt = 0; mt < 4; ++mt) {
                const bf16x4 vf = *(const bf16x4*)&Vs[p][mt * 16 + l15][c * 16 + l4 * 4];
                o_acc[mt] = mfma16(vf, pf[c], o_acc[mt]);
            }
        }

        // write prefetched tile to the other buffer, single barrier
        *(uint4*)&Ks[p ^ 1][srow][scol] = kr0;
        *(uint4*)&Ks[p ^ 1][srow][scol + 8] = kr1;
        *(uint4*)&Vs[p ^ 1][srow][scol] = vr0;
        *(uint4*)&Vs[p ^ 1][srow][scol + 8] = vr1;
        __syncthreads();
        p ^= 1;
    }

    // epilogue: out = x + O^T / l   (dh = mt*16 + l4*4+r, qrow = l15)
    const float inv = 1.0f / l_i;
    const int qrow = q0 + w * 16 + l15;
    #pragma unroll
    for (int mt = 0; mt < 4; ++mt) {
        #pragma unroll
        for (int r = 0; r < 4; ++r) {
            const int d = h * DH_ + mt * 16 + l4 * 4 + r;
            const size_t off = ((size_t)b * T_ + qrow) * D_ + d;
            out[off] = xg[off] + o_acc[mt][r] * inv;
        }
    }
}

extern "C" void kernel_launch(void* const* d_in, const int* in_sizes, int n_in,
                              void* d_out, int out_size, void* d_ws, size_t ws_size,
                              hipStream_t stream) {
    const float* x  = (const float*)d_in[0];
    const float* k  = (const float*)d_in[1];
    const float* v  = (const float*)d_in[2];
    const float* Wq = (const float*)d_in[3];
    float* out = (float*)d_out;

    const size_t NE = (size_t)B_ * H_ * T_ * DH_;   // 4M elements
    unsigned short* kb = (unsigned short*)d_ws;     // 8 MB
    unsigned short* vt = kb + NE;                   // 8 MB
    unsigned short* qb = vt + NE;                   // 8 MB

    fused_prep_qproj<<<2560, 256, 0, stream>>>(k, v, x, Wq, kb, vt, qb);
    attn_kernel<<<1024, 256, 0, stream>>>(qb, kb, vt, x, out);
}